// Round 5
// baseline (131.554 us; speedup 1.0000x reference)
//
#include <hip/hip_runtime.h>
#include <hip/hip_bf16.h>

// VITS length-regulator: attn is one-hot in t per output frame y, so the
// einsums are gathers. Two kernels:
//  1) k_scan_tmap: per-batch ceil(exp(logw))*mask -> shuffle-based scan
//     (2 barriers) -> y_len; binary search per y from LDS cum -> tmap+y_mask.
//  2) k_expand4: 4 channels per block: stage 4 rows of m + exp(logs) in LDS,
//     all loads issued up-front, nontemporal z stores.
//
// Shapes fixed by the problem: B=16, C=192, TX=1024, MAX_Y=4096.

typedef float f32x4 __attribute__((ext_vector_type(4)));

__global__ void __launch_bounds__(1024) k_scan_tmap(
        const float* __restrict__ logw,
        const int* __restrict__ x_lengths,
        int* __restrict__ tmap,
        float* __restrict__ y_mask,
        int tx, int max_y) {
    const int b    = blockIdx.x;
    const int t    = threadIdx.x;       // blockDim.x == tx == 1024
    const int lane = t & 63;
    const int wid  = t >> 6;            // 16 waves
    __shared__ float s[1024];
    __shared__ float wsum[16];
    __shared__ int yl_sh;

    int xl = x_lengths[b];
    if (xl < 1) xl = 1;

    float w = (t < xl) ? ceilf(expf(logw[b * tx + t])) : 0.f;

    // Wave-level inclusive scan (values are integer-valued floats < 2^24:
    // exact in any association order -> bit-matches jnp.cumsum).
    float v = w;
#pragma unroll
    for (int off = 1; off < 64; off <<= 1) {
        float u = __shfl_up(v, off, 64);
        if (lane >= off) v += u;
    }
    if (lane == 63) wsum[wid] = v;
    __syncthreads();

    // Wave 0 scans the 16 wave totals in-register.
    if (wid == 0) {
        float sv = (lane < 16) ? wsum[lane] : 0.f;
#pragma unroll
        for (int off = 1; off < 16; off <<= 1) {
            float u = __shfl_up(sv, off, 64);
            if (lane >= off) sv += u;
        }
        if (lane < 16) wsum[lane] = sv;   // inclusive scan of wave sums
    }
    __syncthreads();

    float cum = v + ((wid > 0) ? wsum[wid - 1] : 0.f);
    s[t] = cum;
    if (t == tx - 1)
        yl_sh = (int)fminf(fmaxf(cum, 1.f), (float)max_y);
    __syncthreads();
    const int yl = yl_sh;

    // Each thread handles 4 consecutive y: binary search in LDS cum.
    const int y0 = t * 4;               // max_y/4 == 1024 == blockDim
    int res[4];
    float msk[4];
#pragma unroll
    for (int k = 0; k < 4; ++k) {
        const int y = y0 + k;
        int r = -1;
        if (y < yl) {
            float fy = (float)y;
            int lo = 0, hi = tx - 1;
            while (lo < hi) {
                int mid = (lo + hi) >> 1;
                if (s[mid] > fy) hi = mid; else lo = mid + 1;
            }
            r = lo;
        }
        res[k] = r;
        msk[k] = (y < yl) ? 1.f : 0.f;
    }
    ((int4*)(tmap + (size_t)b * max_y))[t] =
        make_int4(res[0], res[1], res[2], res[3]);
    ((float4*)(y_mask + (size_t)b * max_y))[t] =
        make_float4(msk[0], msk[1], msk[2], msk[3]);
}

// 4 channels per block, 256 threads, 4 y-vec iterations per channel.
// All global loads issued up-front (fully unrolled, static indexing);
// z written with nontemporal stores (write-once, never re-read).
__global__ void __launch_bounds__(256) k_expand4(
        const float* __restrict__ m_p,
        const float* __restrict__ logs_p,
        const float* __restrict__ noise,
        const int* __restrict__ tmap,
        float* __restrict__ z,
        int C, int tx, int max_y) {
    __shared__ float sm[4][1024];   // m_p rows       (16 KB)
    __shared__ float se[4][1024];   // exp(logs) rows (16 KB)

    const int tid  = threadIdx.x;
    const int cpB  = C >> 2;                   // chunks per batch = 48
    const int b    = blockIdx.x / cpB;
    const int c0   = (blockIdx.x - b * cpB) * 4;
    const size_t row0 = (size_t)b * C + c0;

    // Stage 4 rows of m and exp(logs): 256 threads x float4 each.
#pragma unroll
    for (int r = 0; r < 4; ++r) {
        float4 mv = ((const float4*)(m_p    + (row0 + r) * tx))[tid];
        float4 lv = ((const float4*)(logs_p + (row0 + r) * tx))[tid];
        int j = tid * 4;
        sm[r][j + 0] = mv.x; sm[r][j + 1] = mv.y;
        sm[r][j + 2] = mv.z; sm[r][j + 3] = mv.w;
        se[r][j + 0] = expf(lv.x); se[r][j + 1] = expf(lv.y);
        se[r][j + 2] = expf(lv.z); se[r][j + 3] = expf(lv.w);
    }
    __syncthreads();

    const int4* t4 = (const int4*)(tmap + (size_t)b * max_y);

    // Issue ALL loads first (4 tmap int4 + 16 noise float4 in flight).
    int4   tv[4];
    float4 nv[4][4];
#pragma unroll
    for (int it = 0; it < 4; ++it)
        tv[it] = t4[tid + it * 256];
#pragma unroll
    for (int it = 0; it < 4; ++it) {
        const int i = tid + it * 256;
#pragma unroll
        for (int r = 0; r < 4; ++r)
            nv[it][r] = ((const float4*)(noise + (row0 + r) * max_y))[i];
    }

#pragma unroll
    for (int it = 0; it < 4; ++it) {
        const int i = tid + it * 256;
        const int4 t = tv[it];
#pragma unroll
        for (int r = 0; r < 4; ++r) {
            const float4 n = nv[it][r];
            f32x4 o;
            o.x = (t.x >= 0) ? fmaf(n.x, se[r][t.x], sm[r][t.x]) : n.x;
            o.y = (t.y >= 0) ? fmaf(n.y, se[r][t.y], sm[r][t.y]) : n.y;
            o.z = (t.z >= 0) ? fmaf(n.z, se[r][t.z], sm[r][t.z]) : n.z;
            o.w = (t.w >= 0) ? fmaf(n.w, se[r][t.w], sm[r][t.w]) : n.w;
            __builtin_nontemporal_store(
                o, (f32x4*)(z + (row0 + r) * max_y) + i);
        }
    }
}

extern "C" void kernel_launch(void* const* d_in, const int* in_sizes, int n_in,
                              void* d_out, int out_size, void* d_ws, size_t ws_size,
                              hipStream_t stream) {
    const float* m_p    = (const float*)d_in[0];
    const float* logs_p = (const float*)d_in[1];
    const float* logw   = (const float*)d_in[2];
    const float* noise  = (const float*)d_in[3];
    const int*   x_len  = (const int*)  d_in[4];

    const int B    = in_sizes[4];                 // 16
    const int TX   = in_sizes[2] / B;             // 1024
    const int C    = in_sizes[0] / (B * TX);      // 192
    const int MAXY = in_sizes[3] / (B * C);       // 4096

    float* z      = (float*)d_out;                        // [B, C, MAXY]
    float* y_mask = (float*)d_out + (size_t)B * C * MAXY; // [B, 1, MAXY]

    int* tmap = (int*)d_ws;                       // B*MAXY ints

    k_scan_tmap<<<dim3(B), dim3(1024), 0, stream>>>(
        logw, x_len, tmap, y_mask, TX, MAXY);

    k_expand4<<<dim3(B * (C >> 2)), dim3(256), 0, stream>>>(
        m_p, logs_p, noise, tmap, z, C, TX, MAXY);
}

// Round 6
// 127.429 us; speedup vs baseline: 1.0324x; 1.0324x over previous
//
#include <hip/hip_runtime.h>
#include <hip/hip_bf16.h>

// VITS length-regulator: attn is one-hot in t per output frame y, so the
// einsums are gathers. Two kernels:
//  1) k_scan_tmap: per-batch ceil(exp(logw))*mask -> shuffle-based scan
//     (2 barriers) -> y_len; binary search per y from LDS cum -> tmap+y_mask.
//  2) k_expand3: 2 channels per block (best measured config, R4: 127.9us):
//     stage 2 rows of m + exp(logs) in LDS, all loads issued up-front,
//     regular stores. CPB=4 regressed (occupancy 24->12 waves/CU, R5).
//
// Shapes fixed by the problem: B=16, C=192, TX=1024, MAX_Y=4096.

__global__ void __launch_bounds__(1024) k_scan_tmap(
        const float* __restrict__ logw,
        const int* __restrict__ x_lengths,
        int* __restrict__ tmap,
        float* __restrict__ y_mask,
        int tx, int max_y) {
    const int b    = blockIdx.x;
    const int t    = threadIdx.x;       // blockDim.x == tx == 1024
    const int lane = t & 63;
    const int wid  = t >> 6;            // 16 waves
    __shared__ float s[1024];
    __shared__ float wsum[16];
    __shared__ int yl_sh;

    int xl = x_lengths[b];
    if (xl < 1) xl = 1;

    float w = (t < xl) ? ceilf(expf(logw[b * tx + t])) : 0.f;

    // Wave-level inclusive scan (values are integer-valued floats < 2^24:
    // exact in any association order -> bit-matches jnp.cumsum).
    float v = w;
#pragma unroll
    for (int off = 1; off < 64; off <<= 1) {
        float u = __shfl_up(v, off, 64);
        if (lane >= off) v += u;
    }
    if (lane == 63) wsum[wid] = v;
    __syncthreads();

    // Wave 0 scans the 16 wave totals in-register.
    if (wid == 0) {
        float sv = (lane < 16) ? wsum[lane] : 0.f;
#pragma unroll
        for (int off = 1; off < 16; off <<= 1) {
            float u = __shfl_up(sv, off, 64);
            if (lane >= off) sv += u;
        }
        if (lane < 16) wsum[lane] = sv;   // inclusive scan of wave sums
    }
    __syncthreads();

    float cum = v + ((wid > 0) ? wsum[wid - 1] : 0.f);
    s[t] = cum;
    if (t == tx - 1)
        yl_sh = (int)fminf(fmaxf(cum, 1.f), (float)max_y);
    __syncthreads();
    const int yl = yl_sh;

    // Each thread handles 4 consecutive y: binary search in LDS cum.
    const int y0 = t * 4;               // max_y/4 == 1024 == blockDim
    int res[4];
    float msk[4];
#pragma unroll
    for (int k = 0; k < 4; ++k) {
        const int y = y0 + k;
        int r = -1;
        if (y < yl) {
            float fy = (float)y;
            int lo = 0, hi = tx - 1;
            while (lo < hi) {
                int mid = (lo + hi) >> 1;
                if (s[mid] > fy) hi = mid; else lo = mid + 1;
            }
            r = lo;
        }
        res[k] = r;
        msk[k] = (y < yl) ? 1.f : 0.f;
    }
    ((int4*)(tmap + (size_t)b * max_y))[t] =
        make_int4(res[0], res[1], res[2], res[3]);
    ((float4*)(y_mask + (size_t)b * max_y))[t] =
        make_float4(msk[0], msk[1], msk[2], msk[3]);
}

// 2 channels per block, 256 threads, 4 y-vec iterations per channel.
// All global loads issued up-front (fully unrolled, static indexing).
__global__ void __launch_bounds__(256) k_expand3(
        const float* __restrict__ m_p,
        const float* __restrict__ logs_p,
        const float* __restrict__ noise,
        const int* __restrict__ tmap,
        float* __restrict__ z,
        int C, int tx, int max_y) {
    __shared__ float sm[2][1024];   // m_p rows
    __shared__ float se[2][1024];   // exp(logs_p) rows

    const int tid   = threadIdx.x;
    const int chunk = blockIdx.x;           // 0 .. B*C/2 - 1
    const int b     = chunk / (C >> 1);
    const int c0    = (chunk - b * (C >> 1)) * 2;
    const size_t row0 = (size_t)b * C + c0;

    // Stage 2 rows of m and exp(logs): 256 threads x float4 each.
#pragma unroll
    for (int r = 0; r < 2; ++r) {
        float4 mv = ((const float4*)(m_p    + (row0 + r) * tx))[tid];
        float4 lv = ((const float4*)(logs_p + (row0 + r) * tx))[tid];
        int j = tid * 4;
        sm[r][j + 0] = mv.x; sm[r][j + 1] = mv.y;
        sm[r][j + 2] = mv.z; sm[r][j + 3] = mv.w;
        se[r][j + 0] = expf(lv.x); se[r][j + 1] = expf(lv.y);
        se[r][j + 2] = expf(lv.z); se[r][j + 3] = expf(lv.w);
    }
    __syncthreads();

    const int4* t4 = (const int4*)(tmap + (size_t)b * max_y);

    // 4 iterations x 2 channels; issue ALL loads first, then gather+store.
    int4   tv[4];
    float4 nv[4][2];
#pragma unroll
    for (int it = 0; it < 4; ++it)
        tv[it] = t4[tid + it * 256];
#pragma unroll
    for (int it = 0; it < 4; ++it) {
        const int i = tid + it * 256;
#pragma unroll
        for (int r = 0; r < 2; ++r)
            nv[it][r] = ((const float4*)(noise + (row0 + r) * max_y))[i];
    }

#pragma unroll
    for (int it = 0; it < 4; ++it) {
        const int i = tid + it * 256;
        const int4 t = tv[it];
#pragma unroll
        for (int r = 0; r < 2; ++r) {
            const float4 n = nv[it][r];
            float4 o;
            o.x = (t.x >= 0) ? fmaf(n.x, se[r][t.x], sm[r][t.x]) : n.x;
            o.y = (t.y >= 0) ? fmaf(n.y, se[r][t.y], sm[r][t.y]) : n.y;
            o.z = (t.z >= 0) ? fmaf(n.z, se[r][t.z], sm[r][t.z]) : n.z;
            o.w = (t.w >= 0) ? fmaf(n.w, se[r][t.w], sm[r][t.w]) : n.w;
            ((float4*)(z + (row0 + r) * max_y))[i] = o;
        }
    }
}

extern "C" void kernel_launch(void* const* d_in, const int* in_sizes, int n_in,
                              void* d_out, int out_size, void* d_ws, size_t ws_size,
                              hipStream_t stream) {
    const float* m_p    = (const float*)d_in[0];
    const float* logs_p = (const float*)d_in[1];
    const float* logw   = (const float*)d_in[2];
    const float* noise  = (const float*)d_in[3];
    const int*   x_len  = (const int*)  d_in[4];

    const int B    = in_sizes[4];                 // 16
    const int TX   = in_sizes[2] / B;             // 1024
    const int C    = in_sizes[0] / (B * TX);      // 192
    const int MAXY = in_sizes[3] / (B * C);       // 4096

    float* z      = (float*)d_out;                        // [B, C, MAXY]
    float* y_mask = (float*)d_out + (size_t)B * C * MAXY; // [B, 1, MAXY]

    int* tmap = (int*)d_ws;                       // B*MAXY ints

    k_scan_tmap<<<dim3(B), dim3(1024), 0, stream>>>(
        logw, x_len, tmap, y_mask, TX, MAXY);

    k_expand3<<<dim3(B * (C >> 1)), dim3(256), 0, stream>>>(
        m_p, logs_p, noise, tmap, z, C, TX, MAXY);
}